// Round 1
// baseline (2033.158 us; speedup 1.0000x reference)
//
#include <hip/hip_runtime.h>

#define B_  2
#define N_  4096
#define D_  512
#define H_  8
#define HD_ 64

// ---------------------------------------------------------------------------
// Projection: Y[m][e] = sum_d X[m][d] * W[e][d] + b[e]   (torch Linear, W [out,in])
// M = B*N = 8192 rows. 64x64 tile, K-step 32, 256 threads, 4x4 register block.
// gridDim.z: 0 -> Q (Wq,bq), 1 -> K (Wk,bk)
// ---------------------------------------------------------------------------
__global__ __launch_bounds__(256) void proj_kernel(
    const float* __restrict__ x,
    const float* __restrict__ Wq, const float* __restrict__ bq,
    const float* __restrict__ Wk, const float* __restrict__ bk,
    float* __restrict__ Qout, float* __restrict__ Kout)
{
    const float* W    = blockIdx.z ? Wk : Wq;
    const float* bias = blockIdx.z ? bk : bq;
    float* Y          = blockIdx.z ? Kout : Qout;

    const int m0 = blockIdx.x * 64;
    const int e0 = blockIdx.y * 64;

    __shared__ float Xs[64][36];   // stride 36 keeps float4 alignment + breaks pow2
    __shared__ float Ws[64][36];

    const int tid = threadIdx.x;
    const int tx = tid & 15, ty = tid >> 4;

    float acc[4][4] = {};

    for (int k0 = 0; k0 < D_; k0 += 32) {
        #pragma unroll
        for (int s = 0; s < 2; ++s) {
            int slot = s * 256 + tid;        // 0..511 float4 slots (64 rows x 8)
            int r  = slot >> 3;
            int c4 = (slot & 7) << 2;
            *(float4*)&Xs[r][c4] = *(const float4*)&x[(size_t)(m0 + r) * D_ + k0 + c4];
            *(float4*)&Ws[r][c4] = *(const float4*)&W[(size_t)(e0 + r) * D_ + k0 + c4];
        }
        __syncthreads();
        #pragma unroll
        for (int k = 0; k < 32; k += 4) {
            float4 xa[4], wb[4];
            #pragma unroll
            for (int i = 0; i < 4; ++i) xa[i] = *(float4*)&Xs[ty*4+i][k];
            #pragma unroll
            for (int j = 0; j < 4; ++j) wb[j] = *(float4*)&Ws[tx*4+j][k];
            #pragma unroll
            for (int i = 0; i < 4; ++i)
                #pragma unroll
                for (int j = 0; j < 4; ++j)
                    acc[i][j] += xa[i].x*wb[j].x + xa[i].y*wb[j].y
                               + xa[i].z*wb[j].z + xa[i].w*wb[j].w;
        }
        __syncthreads();
    }

    const float4 bv = *(const float4*)&bias[e0 + tx*4];
    #pragma unroll
    for (int i = 0; i < 4; ++i) {
        float4 o;
        o.x = acc[i][0] + bv.x;
        o.y = acc[i][1] + bv.y;
        o.z = acc[i][2] + bv.z;
        o.w = acc[i][3] + bv.w;
        *(float4*)&Y[(size_t)(m0 + ty*4 + i) * D_ + e0 + tx*4] = o;
    }
}

// ---------------------------------------------------------------------------
// Flash attention, fp32, V = K.
// Block = 256 threads handles one (b, h, 64-row Q tile). 64-key tiles, online
// softmax. K tile stored with XOR swizzle on float4 slots so both the
// QK^T read (rows 4*tx+j, fixed d-slot) and the PV read (fixed row, slot=tx)
// are <=2-way bank accesses.
// ---------------------------------------------------------------------------
__device__ __forceinline__ int swz(int r, int s) { return s ^ ((r >> 2) & 7); }

__global__ __launch_bounds__(256) void attn_kernel(
    const float* __restrict__ Q, const float* __restrict__ K,
    float* __restrict__ out)
{
    const int qt = blockIdx.x;   // 0..63
    const int h  = blockIdx.y;   // 0..7
    const int b  = blockIdx.z;   // 0..1
    const int q0 = qt * 64;

    __shared__ float Qs[64][68];
    __shared__ float Ks[64 * 64];          // swizzled float4 slots, stride 64
    __shared__ float Ss[64][68];
    __shared__ float mS[64], lS[64], aS[64];

    const int tid = threadIdx.x;
    const int tx = tid & 15, ty = tid >> 4;
    const float scale = 0.04419417382415922f;   // 512^-0.5

    // load Q tile (coalesced: 16 lanes cover one contiguous 64-float row)
    #pragma unroll
    for (int s = 0; s < 4; ++s) {
        int slot = s * 256 + tid;          // 0..1023 float4 slots
        int r = slot >> 4, c4 = (slot & 15) << 2;
        *(float4*)&Qs[r][c4] =
            *(const float4*)&Q[(size_t)(b * N_ + q0 + r) * D_ + h * HD_ + c4];
    }
    if (tid < 64) { mS[tid] = -1e30f; lS[tid] = 0.f; }

    float accO[4][4] = {};
    __syncthreads();

    for (int kt = 0; kt < 64; ++kt) {
        const int k0 = kt * 64;

        // ---- load K tile into swizzled LDS ----
        #pragma unroll
        for (int s = 0; s < 4; ++s) {
            int slot = s * 256 + tid;
            int r = slot >> 4, sl = slot & 15;
            *(float4*)&Ks[r * 64 + (swz(r, sl) << 2)] =
                *(const float4*)&K[(size_t)(b * N_ + k0 + r) * D_ + h * HD_ + (sl << 2)];
        }
        __syncthreads();

        // ---- S = scale * Q K^T (64x64), 4x4 per thread ----
        float sa[4][4] = {};
        #pragma unroll
        for (int d = 0; d < 64; d += 4) {
            float4 qa[4], kb[4];
            #pragma unroll
            for (int i = 0; i < 4; ++i) qa[i] = *(float4*)&Qs[ty*4+i][d];
            #pragma unroll
            for (int j = 0; j < 4; ++j) {
                const int r = tx*4 + j;
                kb[j] = *(float4*)&Ks[r * 64 + (swz(r, d >> 2) << 2)];
            }
            #pragma unroll
            for (int i = 0; i < 4; ++i)
                #pragma unroll
                for (int j = 0; j < 4; ++j)
                    sa[i][j] += qa[i].x*kb[j].x + qa[i].y*kb[j].y
                              + qa[i].z*kb[j].z + qa[i].w*kb[j].w;
        }
        #pragma unroll
        for (int i = 0; i < 4; ++i) {
            float4 o;
            o.x = sa[i][0]*scale; o.y = sa[i][1]*scale;
            o.z = sa[i][2]*scale; o.w = sa[i][3]*scale;
            *(float4*)&Ss[ty*4+i][tx*4] = o;
        }
        __syncthreads();

        // ---- online softmax: 4 threads per row, 16 cols each ----
        {
            const int r = tid >> 2, qq = tid & 3;
            float mt = -1e30f;
            #pragma unroll
            for (int c = 0; c < 16; ++c) mt = fmaxf(mt, Ss[r][qq*16 + c]);
            mt = fmaxf(mt, __shfl_xor(mt, 1));
            mt = fmaxf(mt, __shfl_xor(mt, 2));
            const float mold = mS[r];
            const float mnew = fmaxf(mold, mt);
            float lt = 0.f;
            #pragma unroll
            for (int c = 0; c < 16; ++c) {
                float p = __expf(Ss[r][qq*16 + c] - mnew);
                Ss[r][qq*16 + c] = p;
                lt += p;
            }
            lt += __shfl_xor(lt, 1);
            lt += __shfl_xor(lt, 2);
            if (qq == 0) {
                const float alpha = __expf(mold - mnew);
                aS[r] = alpha;
                mS[r] = mnew;
                lS[r] = lS[r] * alpha + lt;
            }
        }
        __syncthreads();

        // ---- O = O*alpha + P @ Ktile  (V = K) ----
        float al[4];
        #pragma unroll
        for (int i = 0; i < 4; ++i) al[i] = aS[ty*4+i];
        #pragma unroll
        for (int i = 0; i < 4; ++i)
            #pragma unroll
            for (int j = 0; j < 4; ++j) accO[i][j] *= al[i];

        #pragma unroll
        for (int kk = 0; kk < 64; kk += 4) {
            float pva[4][4];
            #pragma unroll
            for (int i = 0; i < 4; ++i)
                *(float4*)pva[i] = *(float4*)&Ss[ty*4+i][kk];
            #pragma unroll
            for (int s2 = 0; s2 < 4; ++s2) {
                const int r = kk + s2;
                const float4 kv = *(float4*)&Ks[r * 64 + (swz(r, tx) << 2)];
                #pragma unroll
                for (int i = 0; i < 4; ++i) {
                    accO[i][0] += pva[i][s2] * kv.x;
                    accO[i][1] += pva[i][s2] * kv.y;
                    accO[i][2] += pva[i][s2] * kv.z;
                    accO[i][3] += pva[i][s2] * kv.w;
                }
            }
        }
        __syncthreads();
    }

    // ---- epilogue: divide by l, write out[b, n, h*64+hd] ----
    float linv[4];
    #pragma unroll
    for (int i = 0; i < 4; ++i) linv[i] = 1.0f / lS[ty*4+i];
    #pragma unroll
    for (int i = 0; i < 4; ++i) {
        float4 o;
        o.x = accO[i][0]*linv[i]; o.y = accO[i][1]*linv[i];
        o.z = accO[i][2]*linv[i]; o.w = accO[i][3]*linv[i];
        *(float4*)&out[(size_t)(b * N_ + q0 + ty*4 + i) * D_ + h * HD_ + tx*4] = o;
    }
}

extern "C" void kernel_launch(void* const* d_in, const int* in_sizes, int n_in,
                              void* d_out, int out_size, void* d_ws, size_t ws_size,
                              hipStream_t stream)
{
    const float* x  = (const float*)d_in[0];
    const float* Wq = (const float*)d_in[1];
    const float* bq = (const float*)d_in[2];
    const float* Wk = (const float*)d_in[3];
    const float* bk = (const float*)d_in[4];
    float* outp = (float*)d_out;

    // workspace: Q (16.78 MB) then K (16.78 MB)
    float* Qw = (float*)d_ws;
    float* Kw = Qw + (size_t)B_ * N_ * D_;

    dim3 gp(128, 8, 2);           // (M/64, D/64, {Q,K})
    proj_kernel<<<gp, dim3(256), 0, stream>>>(x, Wq, bq, Wk, bk, Qw, Kw);

    dim3 ga(64, 8, 2);            // (N/64, H, B)
    attn_kernel<<<ga, dim3(256), 0, stream>>>(Qw, Kw, outp);
}

// Round 2
// 671.999 us; speedup vs baseline: 3.0255x; 3.0255x over previous
//
#include <hip/hip_runtime.h>

#define B_  2
#define N_  4096
#define D_  512
#define H_  8
#define HD_ 64
#define SCALE 0.04419417382415922f   // 512^-0.5

typedef float  f32x4  __attribute__((ext_vector_type(4)));
typedef short  s16x8  __attribute__((ext_vector_type(8)));
typedef short  s16x4  __attribute__((ext_vector_type(4)));
typedef unsigned int u32x4 __attribute__((ext_vector_type(4)));

#define MFMA16(a,b,c) __builtin_amdgcn_mfma_f32_16x16x32_bf16((a),(b),(c),0,0,0)

__device__ __forceinline__ unsigned bf16rtn(float x){
    unsigned u = __float_as_uint(x);
    return (u + 0x7FFFu + ((u >> 16) & 1u)) >> 16;
}
__device__ __forceinline__ float bf16tof(unsigned h){
    return __uint_as_float(h << 16);
}
// bf16 [64][64] LDS arrays: XOR-swizzle 8-element blocks within a row so
// stride-128B row-major b128 reads spread across all 32 banks.
__device__ __forceinline__ int ix16(int r, int c){
    return (r << 6) + ((((c >> 3) ^ (r & 7)) << 3) | (c & 7));
}
// packed-P u32 [64][64]: swizzle 4-element (16B) blocks.
__device__ __forceinline__ int ixp(int r, int c){
    return (r << 6) + ((((c >> 2) ^ (r & 15)) << 2) | (c & 3));
}

// ---------------------------------------------------------------------------
// Projection. z==0: Q = x Wq^T + bq  -> fp32.
//            z==1: K = x Wk^T + bk  -> bf16 split (hi, lo) arrays.
// ---------------------------------------------------------------------------
__global__ __launch_bounds__(256) void proj_kernel(
    const float* __restrict__ x,
    const float* __restrict__ Wq, const float* __restrict__ bq,
    const float* __restrict__ Wk, const float* __restrict__ bk,
    float* __restrict__ Qout, short* __restrict__ Khi, short* __restrict__ Klo)
{
    const float* W    = blockIdx.z ? Wk : Wq;
    const float* bias = blockIdx.z ? bk : bq;

    const int m0 = blockIdx.x * 64;
    const int e0 = blockIdx.y * 64;

    __shared__ float Xs[64][36];
    __shared__ float Ws[64][36];

    const int tid = threadIdx.x;
    const int tx = tid & 15, ty = tid >> 4;

    float acc[4][4] = {};

    for (int k0 = 0; k0 < D_; k0 += 32) {
        #pragma unroll
        for (int s = 0; s < 2; ++s) {
            int slot = s * 256 + tid;
            int r  = slot >> 3;
            int c4 = (slot & 7) << 2;
            *(float4*)&Xs[r][c4] = *(const float4*)&x[(size_t)(m0 + r) * D_ + k0 + c4];
            *(float4*)&Ws[r][c4] = *(const float4*)&W[(size_t)(e0 + r) * D_ + k0 + c4];
        }
        __syncthreads();
        #pragma unroll
        for (int k = 0; k < 32; k += 4) {
            float4 xa[4], wb[4];
            #pragma unroll
            for (int i = 0; i < 4; ++i) xa[i] = *(float4*)&Xs[ty*4+i][k];
            #pragma unroll
            for (int j = 0; j < 4; ++j) wb[j] = *(float4*)&Ws[tx*4+j][k];
            #pragma unroll
            for (int i = 0; i < 4; ++i)
                #pragma unroll
                for (int j = 0; j < 4; ++j)
                    acc[i][j] += xa[i].x*wb[j].x + xa[i].y*wb[j].y
                               + xa[i].z*wb[j].z + xa[i].w*wb[j].w;
        }
        __syncthreads();
    }

    const float4 bv = *(const float4*)&bias[e0 + tx*4];
    const float bj[4] = {bv.x, bv.y, bv.z, bv.w};

    if (blockIdx.z == 0) {
        #pragma unroll
        for (int i = 0; i < 4; ++i) {
            float4 o;
            o.x = acc[i][0] + bj[0];
            o.y = acc[i][1] + bj[1];
            o.z = acc[i][2] + bj[2];
            o.w = acc[i][3] + bj[3];
            *(float4*)&Qout[(size_t)(m0 + ty*4 + i) * D_ + e0 + tx*4] = o;
        }
    } else {
        #pragma unroll
        for (int i = 0; i < 4; ++i) {
            s16x4 oh, ol;
            #pragma unroll
            for (int j = 0; j < 4; ++j) {
                float v = acc[i][j] + bj[j];
                unsigned hh = bf16rtn(v);
                float lo = v - bf16tof(hh);
                unsigned ll = bf16rtn(lo);
                oh[j] = (short)hh; ol[j] = (short)ll;
            }
            size_t off = (size_t)(m0 + ty*4 + i) * D_ + e0 + tx*4;
            *(s16x4*)&Khi[off] = oh;
            *(s16x4*)&Klo[off] = ol;
        }
    }
}

// ---------------------------------------------------------------------------
// Flash attention, bf16x3 split-precision MFMA, V = K.
// Block = 4 waves, one 64-row Q tile per (b,h). Wave w owns rows w*16..+15.
// ---------------------------------------------------------------------------
__global__ __launch_bounds__(256, 3) void attn_kernel(
    const float* __restrict__ Q,
    const short* __restrict__ Khi, const short* __restrict__ Klo,
    float* __restrict__ out)
{
    __shared__ short Khs[4096];   // [key][d]  hi
    __shared__ short Kls[4096];   // [key][d]  lo
    __shared__ short Kths[4096];  // [d][key]  hi  (V^T view)
    __shared__ short Ktls[4096];  // [d][key]  lo
    __shared__ unsigned Pp[4096]; // [q][key] packed hi|lo<<16

    // XCD-chunked swizzle: 2 consecutive (b,h) per XCD -> K set (2MB) L2-resident
    const int bid = blockIdx.x;
    const int xcd = bid & 7, kk_ = bid >> 3;
    const int qt = kk_ & 63;
    const int bh = (xcd << 1) | (kk_ >> 6);
    const int b = bh >> 3, h = bh & 7;
    const int q0 = qt * 64;

    const int tid  = threadIdx.x;
    const int wave = tid >> 6, lane = tid & 63;
    const int lr = lane & 15, lg = lane >> 4;

    // ---- Q A-frags in registers, pre-scaled, split hi/lo ----
    s16x8 qh[2], ql[2];
    {
        const int qrow = q0 + wave*16 + lr;
        const float* qp = Q + ((size_t)(b*N_ + qrow)) * D_ + h*HD_;
        #pragma unroll
        for (int ks = 0; ks < 2; ++ks) {
            const float* p = qp + ks*32 + lg*8;
            float4 a = *(const float4*)p;
            float4 c = *(const float4*)(p + 4);
            float v[8] = {a.x,a.y,a.z,a.w,c.x,c.y,c.z,c.w};
            #pragma unroll
            for (int j = 0; j < 8; ++j) {
                float xv = v[j] * SCALE;
                unsigned hh = bf16rtn(xv);
                float lo = xv - bf16tof(hh);
                unsigned ll = bf16rtn(lo);
                qh[ks][j] = (short)hh; ql[ks][j] = (short)ll;
            }
        }
    }

    f32x4 oacc[4] = {};
    float mrun[4], lrun[4];
    #pragma unroll
    for (int r = 0; r < 4; ++r) { mrun[r] = -1e30f; lrun[r] = 0.f; }

    const int br = tid >> 4, bc = tid & 15;   // staging: 4x4 block per thread

    for (int kt = 0; kt < 64; ++kt) {
        // ---- stage K tile: rows + in-register 4x4 transpose ----
        {
            const size_t kbase = ((size_t)(b*N_ + kt*64 + br*4)) * D_ + h*HD_ + bc*4;
            s16x4 rh[4], rl[4];
            #pragma unroll
            for (int i = 0; i < 4; ++i) {
                rh[i] = *(const s16x4*)&Khi[kbase + (size_t)i * D_];
                rl[i] = *(const s16x4*)&Klo[kbase + (size_t)i * D_];
            }
            #pragma unroll
            for (int i = 0; i < 4; ++i) {
                *(s16x4*)&Khs[ix16(br*4+i, bc*4)] = rh[i];
                *(s16x4*)&Kls[ix16(br*4+i, bc*4)] = rl[i];
            }
            #pragma unroll
            for (int j = 0; j < 4; ++j) {
                s16x4 th = { rh[0][j], rh[1][j], rh[2][j], rh[3][j] };
                s16x4 tl = { rl[0][j], rl[1][j], rl[2][j], rl[3][j] };
                *(s16x4*)&Kths[ix16(bc*4+j, br*4)] = th;
                *(s16x4*)&Ktls[ix16(bc*4+j, br*4)] = tl;
            }
        }
        __syncthreads();

        // ---- S = Q' K^T : 4 col-tiles, bf16x3 ----
        f32x4 sacc[4] = {};
        #pragma unroll
        for (int ks = 0; ks < 2; ++ks) {
            s16x8 kbh[4], kbl[4];
            #pragma unroll
            for (int t = 0; t < 4; ++t) {
                const int n = t*16 + lr;
                const int c = ks*32 + lg*8;
                kbh[t] = *(const s16x8*)&Khs[ix16(n, c)];
                kbl[t] = *(const s16x8*)&Kls[ix16(n, c)];
            }
            #pragma unroll
            for (int t = 0; t < 4; ++t) sacc[t] = MFMA16(qh[ks], kbh[t], sacc[t]);
            #pragma unroll
            for (int t = 0; t < 4; ++t) sacc[t] = MFMA16(qh[ks], kbl[t], sacc[t]);
            #pragma unroll
            for (int t = 0; t < 4; ++t) sacc[t] = MFMA16(ql[ks], kbh[t], sacc[t]);
        }

        // ---- online softmax in C-layout registers ----
        float mt[4];
        #pragma unroll
        for (int r = 0; r < 4; ++r)
            mt[r] = fmaxf(fmaxf(sacc[0][r], sacc[1][r]), fmaxf(sacc[2][r], sacc[3][r]));
        #pragma unroll
        for (int r = 0; r < 4; ++r) {
            #pragma unroll
            for (int msk = 1; msk < 16; msk <<= 1)
                mt[r] = fmaxf(mt[r], __shfl_xor(mt[r], msk));
        }
        float alpha[4];
        #pragma unroll
        for (int r = 0; r < 4; ++r) {
            float mn = fmaxf(mrun[r], mt[r]);
            alpha[r] = __expf(mrun[r] - mn);
            mrun[r] = mn;
        }
        float p[4][4], rs[4] = {0.f, 0.f, 0.f, 0.f};
        #pragma unroll
        for (int t = 0; t < 4; ++t)
            #pragma unroll
            for (int r = 0; r < 4; ++r) {
                p[t][r] = __expf(sacc[t][r] - mrun[r]);
                rs[r] += p[t][r];
            }
        #pragma unroll
        for (int r = 0; r < 4; ++r) {
            #pragma unroll
            for (int msk = 1; msk < 16; msk <<= 1)
                rs[r] += __shfl_xor(rs[r], msk);
            lrun[r] = lrun[r] * alpha[r] + rs[r];
        }
        #pragma unroll
        for (int t = 0; t < 4; ++t)
            #pragma unroll
            for (int r = 0; r < 4; ++r)
                oacc[t][r] *= alpha[r];

        // ---- P -> packed LDS (per-wave private rows) ----
        #pragma unroll
        for (int t = 0; t < 4; ++t)
            #pragma unroll
            for (int r = 0; r < 4; ++r) {
                const int row = wave*16 + lg*4 + r;
                const int kc  = t*16 + lr;
                unsigned hh = bf16rtn(p[t][r]);
                float lo = p[t][r] - bf16tof(hh);
                unsigned ll = bf16rtn(lo);
                Pp[ixp(row, kc)] = hh | (ll << 16);
            }
        __syncthreads();

        // ---- O += P V  (V = K via Kt), bf16x3 ----
        #pragma unroll
        for (int ks = 0; ks < 2; ++ks) {
            const int kk0  = ks*32 + lg*8;
            const int prow = wave*16 + lr;
            u32x4 a = *(const u32x4*)&Pp[ixp(prow, kk0)];
            u32x4 c = *(const u32x4*)&Pp[ixp(prow, kk0 + 4)];
            s16x8 pah, pal;
            #pragma unroll
            for (int i = 0; i < 4; ++i) {
                pah[i]   = (short)(a[i] & 0xFFFFu);
                pal[i]   = (short)(a[i] >> 16);
                pah[4+i] = (short)(c[i] & 0xFFFFu);
                pal[4+i] = (short)(c[i] >> 16);
            }
            s16x8 vbh[4], vbl[4];
            #pragma unroll
            for (int t = 0; t < 4; ++t) {
                const int e = t*16 + lr;
                vbh[t] = *(const s16x8*)&Kths[ix16(e, kk0)];
                vbl[t] = *(const s16x8*)&Ktls[ix16(e, kk0)];
            }
            #pragma unroll
            for (int t = 0; t < 4; ++t) oacc[t] = MFMA16(pah, vbh[t], oacc[t]);
            #pragma unroll
            for (int t = 0; t < 4; ++t) oacc[t] = MFMA16(pah, vbl[t], oacc[t]);
            #pragma unroll
            for (int t = 0; t < 4; ++t) oacc[t] = MFMA16(pal, vbh[t], oacc[t]);
        }
        __syncthreads();
    }

    // ---- epilogue: O /= l ----
    #pragma unroll
    for (int r = 0; r < 4; ++r) {
        const float inv = 1.0f / lrun[r];
        const int row = q0 + wave*16 + lg*4 + r;
        float* op = out + ((size_t)(b*N_ + row)) * D_ + h*HD_;
        #pragma unroll
        for (int t = 0; t < 4; ++t)
            op[t*16 + lr] = oacc[t][r] * inv;
    }
}

extern "C" void kernel_launch(void* const* d_in, const int* in_sizes, int n_in,
                              void* d_out, int out_size, void* d_ws, size_t ws_size,
                              hipStream_t stream)
{
    const float* x  = (const float*)d_in[0];
    const float* Wq = (const float*)d_in[1];
    const float* bq = (const float*)d_in[2];
    const float* Wk = (const float*)d_in[3];
    const float* bk = (const float*)d_in[4];
    float* outp = (float*)d_out;

    // workspace: Q fp32 (16.78 MB) | Khi bf16 (8.39 MB) | Klo bf16 (8.39 MB)
    float* Qw  = (float*)d_ws;
    short* Khi = (short*)(Qw + (size_t)B_ * N_ * D_);
    short* Klo = Khi + (size_t)B_ * N_ * D_;

    dim3 gp(128, 8, 2);
    proj_kernel<<<gp, dim3(256), 0, stream>>>(x, Wq, bq, Wk, bk, Qw, Khi, Klo);

    attn_kernel<<<dim3(1024), dim3(256), 0, stream>>>(Qw, Khi, Klo, outp);
}

// Round 4
// 668.936 us; speedup vs baseline: 3.0394x; 1.0046x over previous
//
#include <hip/hip_runtime.h>

#define B_  2
#define N_  4096
#define D_  512
#define H_  8
#define HD_ 64
// (D^-0.5) * log2(e): fold softmax scale AND exp->exp2 conversion into Q
#define SCL2 (0.04419417382415922f * 1.4426950408889634f)

typedef float  f32x4  __attribute__((ext_vector_type(4)));
typedef short  s16x8  __attribute__((ext_vector_type(8)));
typedef short  s16x4  __attribute__((ext_vector_type(4)));
typedef unsigned int u32x4 __attribute__((ext_vector_type(4)));

#define MFMA16(a,b,c) __builtin_amdgcn_mfma_f32_16x16x32_bf16((a),(b),(c),0,0,0)

__device__ __forceinline__ unsigned bf16rtn(float x){
    unsigned u = __float_as_uint(x);
    return (u + 0x7FFFu + ((u >> 16) & 1u)) >> 16;
}
__device__ __forceinline__ float bf16tof(unsigned h){
    return __uint_as_float(h << 16);
}
// direct [64][64] bf16 arrays: XOR-swizzle 8-elem (16B) blocks with row&7
__device__ __forceinline__ int ix16(int r, int c){
    return (r << 6) + ((((c >> 3) ^ (r & 7)) << 3) | (c & 7));
}
// transposed arrays: extra ^(r>>3) so transpose-WRITES (rows 4*bc+j) spread
// over all 32 banks (row*128B == 0 mod 32 words; row&7 alone only sees bc&1)
__device__ __forceinline__ int ixt(int r, int c){
    return (r << 6) + ((((c >> 3) ^ (r & 7) ^ ((r >> 3) & 7)) << 3) | (c & 7));
}
// packed-P u32 [128][64]: swizzle 4-elem (16B) blocks with row&15
__device__ __forceinline__ int ixp(int r, int c){
    return (r << 6) + ((((c >> 2) ^ (r & 15)) << 2) | (c & 3));
}

// ---------------------------------------------------------------------------
// Projection: 128x128 tile, 8x8 per thread. Ws XOR-swizzled (plain stride had
// 16 lanes on one 4-bank group: 288*tx mod 32 == 0). Xs reads are broadcasts.
// z==0: Q = x Wq^T + bq -> fp32.  z==1: K = x Wk^T + bk -> bf16 hi/lo split.
// ---------------------------------------------------------------------------
__global__ __launch_bounds__(256) void proj_kernel(
    const float* __restrict__ x,
    const float* __restrict__ Wq, const float* __restrict__ bq,
    const float* __restrict__ Wk, const float* __restrict__ bk,
    float* __restrict__ Qout, short* __restrict__ Khi, short* __restrict__ Klo)
{
    const float* W    = blockIdx.z ? Wk : Wq;
    const float* bias = blockIdx.z ? bk : bq;

    const int m0 = blockIdx.x * 128;
    const int e0 = blockIdx.y * 128;

    __shared__ float Xs[128][36];
    __shared__ float Ws[128 * 36];   // swizzled 4-float blocks

    const int tid = threadIdx.x;
    const int tx = tid & 15, ty = tid >> 4;

    float acc[8][8] = {};

    for (int k0 = 0; k0 < D_; k0 += 32) {
        #pragma unroll
        for (int s = 0; s < 4; ++s) {
            int slot = s * 256 + tid;          // 1024 float4 slots (128 x 8)
            int r  = slot >> 3;
            int c4 = (slot & 7) << 2;
            *(float4*)&Xs[r][c4] = *(const float4*)&x[(size_t)(m0 + r) * D_ + k0 + c4];
            int wblk = ((c4 >> 2) ^ (r >> 3)) & 7;
            *(float4*)&Ws[r * 36 + wblk * 4] = *(const float4*)&W[(size_t)(e0 + r) * D_ + k0 + c4];
        }
        __syncthreads();
        #pragma unroll
        for (int k = 0; k < 32; k += 4) {
            float4 xa[8], wb[8];
            #pragma unroll
            for (int i = 0; i < 8; ++i) xa[i] = *(float4*)&Xs[ty*8+i][k];
            #pragma unroll
            for (int j = 0; j < 8; ++j) {
                int row = tx*8 + j;
                int blk = ((k >> 2) ^ (row >> 3)) & 7;
                wb[j] = *(float4*)&Ws[row * 36 + blk * 4];
            }
            #pragma unroll
            for (int i = 0; i < 8; ++i)
                #pragma unroll
                for (int j = 0; j < 8; ++j)
                    acc[i][j] += xa[i].x*wb[j].x + xa[i].y*wb[j].y
                               + xa[i].z*wb[j].z + xa[i].w*wb[j].w;
        }
        __syncthreads();
    }

    const float4 bv0 = *(const float4*)&bias[e0 + tx*8];
    const float4 bv1 = *(const float4*)&bias[e0 + tx*8 + 4];
    const float bj[8] = {bv0.x,bv0.y,bv0.z,bv0.w, bv1.x,bv1.y,bv1.z,bv1.w};

    if (blockIdx.z == 0) {
        #pragma unroll
        for (int i = 0; i < 8; ++i) {
            float o[8];
            #pragma unroll
            for (int j = 0; j < 8; ++j) o[j] = acc[i][j] + bj[j];
            size_t off = (size_t)(m0 + ty*8 + i) * D_ + e0 + tx*8;
            *(float4*)&Qout[off]     = *(float4*)&o[0];
            *(float4*)&Qout[off + 4] = *(float4*)&o[4];
        }
    } else {
        #pragma unroll
        for (int i = 0; i < 8; ++i) {
            s16x8 oh, ol;
            #pragma unroll
            for (int j = 0; j < 8; ++j) {
                float v = acc[i][j] + bj[j];
                unsigned hh = bf16rtn(v);
                float lo = v - bf16tof(hh);
                unsigned ll = bf16rtn(lo);
                oh[j] = (short)hh; ol[j] = (short)ll;
            }
            size_t off = (size_t)(m0 + ty*8 + i) * D_ + e0 + tx*8;
            *(s16x8*)&Khi[off] = oh;    // off is 8-elem (16B) aligned
            *(s16x8*)&Klo[off] = ol;
        }
    }
}

// ---------------------------------------------------------------------------
// Flash attention, bf16x3 split MFMA, V = K. QBLK=128 (4 waves x 2 q-frags),
// KVBLK=64, software-prefetched K staging, 2 barriers/iter.
// ---------------------------------------------------------------------------
__global__ __launch_bounds__(256, 2) void attn_kernel(
    const float* __restrict__ Q,
    const short* __restrict__ Khi, const short* __restrict__ Klo,
    float* __restrict__ out)
{
    __shared__ short Khs[4096];      // [key][d] hi   (ix16)
    __shared__ short Kls[4096];      // [key][d] lo
    __shared__ short Kths[4096];     // [d][key] hi   (ixt)
    __shared__ short Ktls[4096];     // [d][key] lo
    __shared__ unsigned Pp[8192];    // [128 q][64 k] packed hi<<16|... (ixp)

    // XCD-chunked swizzle: 2 (b,h) per XCD -> K panel (2MB) stays L2-resident
    const int bid = blockIdx.x;
    const int xcd = bid & 7, kk = bid >> 3;        // kk 0..63
    const int bh  = (xcd << 1) | (kk >> 5);
    const int qt  = kk & 31;
    const int b = bh >> 3, h = bh & 7;
    const int q0 = qt * 128;

    const int tid  = threadIdx.x;
    const int wave = tid >> 6, lane = tid & 63;
    const int lr = lane & 15, lg = lane >> 4;

    // ---- Q A-frags in registers: pre-scaled by D^-0.5 * log2(e), RTN split ----
    s16x8 qh[2][2], ql[2][2];
    #pragma unroll
    for (int f = 0; f < 2; ++f) {
        const int qrow = q0 + wave*32 + f*16 + lr;
        const float* qp = Q + ((size_t)(b*N_ + qrow)) * D_ + h*HD_;
        #pragma unroll
        for (int ks = 0; ks < 2; ++ks) {
            const float* p = qp + ks*32 + lg*8;
            float4 a = *(const float4*)p;
            float4 c = *(const float4*)(p + 4);
            float v[8] = {a.x,a.y,a.z,a.w,c.x,c.y,c.z,c.w};
            #pragma unroll
            for (int j = 0; j < 8; ++j) {
                float xv = v[j] * SCL2;
                unsigned hh = bf16rtn(xv);
                float lo = xv - bf16tof(hh);
                unsigned ll = bf16rtn(lo);
                qh[f][ks][j] = (short)hh; ql[f][ks][j] = (short)ll;
            }
        }
    }

    f32x4 oacc[2][4] = {};
    float mrun[2][4], lrun[2][4];
    #pragma unroll
    for (int f = 0; f < 2; ++f)
        #pragma unroll
        for (int r = 0; r < 4; ++r) { mrun[f][r] = -1e30f; lrun[f][r] = 0.f; }

    const int br = tid >> 4, bc = tid & 15;   // staging: 4x4 block per thread
    s16x4 rh[4], rl[4];                        // prefetch registers

    {   // prefetch tile 0
        const size_t kbase = ((size_t)(b*N_ + br*4)) * D_ + h*HD_ + bc*4;
        #pragma unroll
        for (int i = 0; i < 4; ++i) {
            rh[i] = *(const s16x4*)&Khi[kbase + (size_t)i * D_];
            rl[i] = *(const s16x4*)&Klo[kbase + (size_t)i * D_];
        }
    }

    for (int kt = 0; kt < 64; ++kt) {
        // ---- stage prefetched K tile (direct + transposed) ----
        #pragma unroll
        for (int i = 0; i < 4; ++i) {
            *(s16x4*)&Khs[ix16(br*4+i, bc*4)] = rh[i];
            *(s16x4*)&Kls[ix16(br*4+i, bc*4)] = rl[i];
        }
        #pragma unroll
        for (int j = 0; j < 4; ++j) {
            s16x4 th = { rh[0][j], rh[1][j], rh[2][j], rh[3][j] };
            s16x4 tl = { rl[0][j], rl[1][j], rl[2][j], rl[3][j] };
            *(s16x4*)&Kths[ixt(bc*4+j, br*4)] = th;
            *(s16x4*)&Ktls[ixt(bc*4+j, br*4)] = tl;
        }
        __syncthreads();

        // ---- prefetch next tile (latency hides under this iter's compute) ----
        if (kt < 63) {
            const size_t kbase = ((size_t)(b*N_ + (kt+1)*64 + br*4)) * D_ + h*HD_ + bc*4;
            #pragma unroll
            for (int i = 0; i < 4; ++i) {
                rh[i] = *(const s16x4*)&Khi[kbase + (size_t)i * D_];
                rl[i] = *(const s16x4*)&Klo[kbase + (size_t)i * D_];
            }
        }

        // ---- S = Q' K^T : bf16x3, 2 q-frags x 4 col-tiles ----
        f32x4 sacc[2][4] = {};
        __builtin_amdgcn_s_setprio(1);
        #pragma unroll
        for (int ks = 0; ks < 2; ++ks) {
            s16x8 kbh[4], kbl[4];
            #pragma unroll
            for (int t = 0; t < 4; ++t) {
                kbh[t] = *(const s16x8*)&Khs[ix16(t*16+lr, ks*32+lg*8)];
                kbl[t] = *(const s16x8*)&Kls[ix16(t*16+lr, ks*32+lg*8)];
            }
            #pragma unroll
            for (int f = 0; f < 2; ++f) {
                #pragma unroll
                for (int t = 0; t < 4; ++t) sacc[f][t] = MFMA16(qh[f][ks], kbh[t], sacc[f][t]);
                #pragma unroll
                for (int t = 0; t < 4; ++t) sacc[f][t] = MFMA16(qh[f][ks], kbl[t], sacc[f][t]);
                #pragma unroll
                for (int t = 0; t < 4; ++t) sacc[f][t] = MFMA16(ql[f][ks], kbh[t], sacc[f][t]);
            }
        }
        __builtin_amdgcn_s_setprio(0);

        // ---- online softmax (base-2 units) + packed-P store ----
        #pragma unroll
        for (int f = 0; f < 2; ++f) {
            float mt[4];
            #pragma unroll
            for (int r = 0; r < 4; ++r)
                mt[r] = fmaxf(fmaxf(sacc[f][0][r], sacc[f][1][r]),
                              fmaxf(sacc[f][2][r], sacc[f][3][r]));
            #pragma unroll
            for (int r = 0; r < 4; ++r)
                #pragma unroll
                for (int msk = 1; msk < 16; msk <<= 1)
                    mt[r] = fmaxf(mt[r], __shfl_xor(mt[r], msk));
            float al[4];
            #pragma unroll
            for (int r = 0; r < 4; ++r) {
                float mn = fmaxf(mrun[f][r], mt[r]);
                al[r] = __builtin_amdgcn_exp2f(mrun[f][r] - mn);
                mrun[f][r] = mn;
            }
            float rs[4] = {0.f, 0.f, 0.f, 0.f};
            #pragma unroll
            for (int t = 0; t < 4; ++t)
                #pragma unroll
                for (int r = 0; r < 4; ++r) {
                    float p = __builtin_amdgcn_exp2f(sacc[f][t][r] - mrun[f][r]);
                    rs[r] += p;
                    // cheap truncation split: hi = top16(p), lo = p - hi (exact)
                    unsigned u  = __float_as_uint(p);
                    unsigned uh = u & 0xFFFF0000u;
                    unsigned ul = __float_as_uint(p - __uint_as_float(uh));
                    Pp[ixp(wave*32 + f*16 + lg*4 + r, t*16 + lr)] = uh | (ul >> 16);
                }
            #pragma unroll
            for (int r = 0; r < 4; ++r) {
                #pragma unroll
                for (int msk = 1; msk < 16; msk <<= 1)
                    rs[r] += __shfl_xor(rs[r], msk);
                lrun[f][r] = lrun[f][r] * al[r] + rs[r];
            }
            #pragma unroll
            for (int t = 0; t < 4; ++t)
                #pragma unroll
                for (int r = 0; r < 4; ++r)
                    oacc[f][t][r] *= al[r];
        }
        // no barrier: Pp rows are wave-private; in-wave DS ops are in-order

        // ---- O += P V  (V = K via Kt), bf16x3 ----
        __builtin_amdgcn_s_setprio(1);
        #pragma unroll
        for (int ks = 0; ks < 2; ++ks) {
            s16x8 vbh[4], vbl[4];
            #pragma unroll
            for (int t = 0; t < 4; ++t) {
                vbh[t] = *(const s16x8*)&Kths[ixt(t*16+lr, ks*32+lg*8)];
                vbl[t] = *(const s16x8*)&Ktls[ixt(t*16+lr, ks*32+lg*8)];
            }
            #pragma unroll
            for (int f = 0; f < 2; ++f) {
                const int prow = wave*32 + f*16 + lr;
                u32x4 a = *(const u32x4*)&Pp[ixp(prow, ks*32 + lg*8)];
                u32x4 c = *(const u32x4*)&Pp[ixp(prow, ks*32 + lg*8 + 4)];
                s16x8 pah, pal;
                #pragma unroll
                for (int i = 0; i < 4; ++i) {
                    pah[i]   = (short)(a[i] >> 16);
                    pal[i]   = (short)(a[i] & 0xFFFFu);
                    pah[4+i] = (short)(c[i] >> 16);
                    pal[4+i] = (short)(c[i] & 0xFFFFu);
                }
                #pragma unroll
                for (int t = 0; t < 4; ++t) oacc[f][t] = MFMA16(pah, vbh[t], oacc[f][t]);
                #pragma unroll
                for (int t = 0; t < 4; ++t) oacc[f][t] = MFMA16(pah, vbl[t], oacc[f][t]);
                #pragma unroll
                for (int t = 0; t < 4; ++t) oacc[f][t] = MFMA16(pal, vbh[t], oacc[f][t]);
            }
        }
        __builtin_amdgcn_s_setprio(0);
        __syncthreads();   // all K-LDS reads done before next stage overwrite
    }

    // ---- epilogue: O /= l ----
    #pragma unroll
    for (int f = 0; f < 2; ++f)
        #pragma unroll
        for (int r = 0; r < 4; ++r) {
            const float inv = 1.0f / lrun[f][r];
            const int row = q0 + wave*32 + f*16 + lg*4 + r;
            float* op = out + ((size_t)(b*N_ + row)) * D_ + h*HD_;
            #pragma unroll
            for (int t = 0; t < 4; ++t)
                op[t*16 + lr] = oacc[f][t][r] * inv;
        }
}

extern "C" void kernel_launch(void* const* d_in, const int* in_sizes, int n_in,
                              void* d_out, int out_size, void* d_ws, size_t ws_size,
                              hipStream_t stream)
{
    const float* x  = (const float*)d_in[0];
    const float* Wq = (const float*)d_in[1];
    const float* bq = (const float*)d_in[2];
    const float* Wk = (const float*)d_in[3];
    const float* bk = (const float*)d_in[4];
    float* outp = (float*)d_out;

    // workspace: Q fp32 (16.78 MB) | Khi bf16 (8.39 MB) | Klo bf16 (8.39 MB)
    float* Qw  = (float*)d_ws;
    short* Khi = (short*)(Qw + (size_t)B_ * N_ * D_);
    short* Klo = Khi + (size_t)B_ * N_ * D_;

    dim3 gp(64, 4, 2);            // (8192/128, 512/128, {Q,K})
    proj_kernel<<<gp, dim3(256), 0, stream>>>(x, Wq, bq, Wk, bk, Qw, Khi, Klo);

    attn_kernel<<<dim3(512), dim3(256), 0, stream>>>(Qw, Khi, Klo, outp);
}

// Round 5
// 371.473 us; speedup vs baseline: 5.4732x; 1.8008x over previous
//
#include <hip/hip_runtime.h>

#define B_  2
#define N_  4096
#define D_  512
#define H_  8
#define HD_ 64
// (D^-0.5) * log2(e): fold softmax scale AND exp->exp2 conversion into Q
#define SCL2 (0.04419417382415922f * 1.4426950408889634f)

typedef float  f32x4  __attribute__((ext_vector_type(4)));
typedef short  s16x8  __attribute__((ext_vector_type(8)));
typedef short  s16x4  __attribute__((ext_vector_type(4)));
typedef unsigned int u32x4 __attribute__((ext_vector_type(4)));

#define MFMA16(a,b,c) __builtin_amdgcn_mfma_f32_16x16x32_bf16((a),(b),(c),0,0,0)

__device__ __forceinline__ unsigned bf16rtn(float x){
    unsigned u = __float_as_uint(x);
    return (u + 0x7FFFu + ((u >> 16) & 1u)) >> 16;
}
__device__ __forceinline__ float bf16tof(unsigned h){
    return __uint_as_float(h << 16);
}
// [*][64] bf16 arrays: XOR-swizzle 8-elem (16B) blocks with row&7
__device__ __forceinline__ int ix16(int r, int c){
    return (r << 6) + ((((c >> 3) ^ (r & 7)) << 3) | (c & 7));
}
// transposed arrays: extra ^(r>>3) so transpose-WRITES (rows 4*bc+j) spread
// over all 32 banks (row*128B == 0 mod 32 words; row&7 alone only sees bc&1)
__device__ __forceinline__ int ixt(int r, int c){
    return (r << 6) + ((((c >> 3) ^ (r & 7) ^ ((r >> 3) & 7)) << 3) | (c & 7));
}
// packed-P u32 [128][64]: swizzle 4-elem (16B) blocks with row&15
__device__ __forceinline__ int ixp(int r, int c){
    return (r << 6) + ((((c >> 2) ^ (r & 15)) << 2) | (c & 3));
}

// ---------------------------------------------------------------------------
// Split pass: fp32 -> (bf16 hi, bf16 lo) for x, Wq, Wk. Pure streaming.
// blocks [0,2048): x (4.19M elems); [2048,2176): Wq; [2176,2304): Wk.
// ---------------------------------------------------------------------------
__global__ __launch_bounds__(256) void split_kernel(
    const float* __restrict__ x, const float* __restrict__ Wq, const float* __restrict__ Wk,
    short* __restrict__ xh, short* __restrict__ xl,
    short* __restrict__ wqh, short* __restrict__ wql,
    short* __restrict__ wkh, short* __restrict__ wkl)
{
    const int bid = blockIdx.x;
    const float* src; short* dh; short* dl; size_t base;
    if (bid < 2048)      { src = x;  dh = xh;  dl = xl;  base = (size_t)bid * 2048; }
    else if (bid < 2176) { src = Wq; dh = wqh; dl = wql; base = (size_t)(bid - 2048) * 2048; }
    else                 { src = Wk; dh = wkh; dl = wkl; base = (size_t)(bid - 2176) * 2048; }

    const size_t off = base + (size_t)threadIdx.x * 8;
    float4 a = *(const float4*)&src[off];
    float4 c = *(const float4*)&src[off + 4];
    float v[8] = {a.x,a.y,a.z,a.w, c.x,c.y,c.z,c.w};
    s16x8 oh, ol;
    #pragma unroll
    for (int j = 0; j < 8; ++j) {
        unsigned hh = bf16rtn(v[j]);
        float lo = v[j] - bf16tof(hh);
        unsigned ll = bf16rtn(lo);
        oh[j] = (short)hh; ol[j] = (short)ll;
    }
    *(s16x8*)&dh[off] = oh;
    *(s16x8*)&dl[off] = ol;
}

// ---------------------------------------------------------------------------
// Projection GEMM on MFMA, bf16x3 split precision.
// Y[m][e] = sum_d x[m][d]*W[e][d] + b[e].  Tile 128(M) x 128(E), BK=64,
// 4 waves x (2 row-frags x 8 col-frags), register-prefetched staging.
// z==0: Q -> fp32.   z==1: K -> bf16 hi/lo split (what attn consumes).
// ---------------------------------------------------------------------------
__global__ __launch_bounds__(256, 2) void proj_gemm(
    const short* __restrict__ xh, const short* __restrict__ xl,
    const short* __restrict__ wqh, const short* __restrict__ wql,
    const short* __restrict__ wkh, const short* __restrict__ wkl,
    const float* __restrict__ bq, const float* __restrict__ bk,
    float* __restrict__ Qout, short* __restrict__ Khi, short* __restrict__ Klo)
{
    __shared__ short Ah[8192], Al[8192], Bh[8192], Bl[8192];   // [128][64] ix16

    const short* gWh  = blockIdx.z ? wkh : wqh;
    const short* gWl  = blockIdx.z ? wkl : wql;
    const float* bias = blockIdx.z ? bk  : bq;

    const int m0 = blockIdx.x * 128;
    const int e0 = blockIdx.y * 128;
    const int tid = threadIdx.x;
    const int wave = tid >> 6, lane = tid & 63;
    const int lr = lane & 15, lg = lane >> 4;

    // staging slots: 4 s16x8 per thread per array
    int srow[4], scol[4];
    #pragma unroll
    for (int s = 0; s < 4; ++s) {
        int slot = s * 256 + tid;
        srow[s] = slot >> 3;
        scol[s] = (slot & 7) << 3;
    }

    f32x4 acc[2][8] = {};
    s16x8 pah[4], pal[4], pbh[4], pbl[4];

    #pragma unroll
    for (int s = 0; s < 4; ++s) {     // prefetch K-step 0
        size_t ao = (size_t)(m0 + srow[s]) * D_ + scol[s];
        size_t bo = (size_t)(e0 + srow[s]) * D_ + scol[s];
        pah[s] = *(const s16x8*)&xh[ao];  pal[s] = *(const s16x8*)&xl[ao];
        pbh[s] = *(const s16x8*)&gWh[bo]; pbl[s] = *(const s16x8*)&gWl[bo];
    }

    for (int kt = 0; kt < 8; ++kt) {
        if (kt) __syncthreads();                // prior compute done
        #pragma unroll
        for (int s = 0; s < 4; ++s) {
            int d = ix16(srow[s], scol[s]);
            *(s16x8*)&Ah[d] = pah[s];  *(s16x8*)&Al[d] = pal[s];
            *(s16x8*)&Bh[d] = pbh[s];  *(s16x8*)&Bl[d] = pbl[s];
        }
        __syncthreads();
        if (kt < 7) {                            // prefetch next K-step
            const int k0 = (kt + 1) * 64;
            #pragma unroll
            for (int s = 0; s < 4; ++s) {
                size_t ao = (size_t)(m0 + srow[s]) * D_ + k0 + scol[s];
                size_t bo = (size_t)(e0 + srow[s]) * D_ + k0 + scol[s];
                pah[s] = *(const s16x8*)&xh[ao];  pal[s] = *(const s16x8*)&xl[ao];
                pbh[s] = *(const s16x8*)&gWh[bo]; pbl[s] = *(const s16x8*)&gWl[bo];
            }
        }
        __builtin_amdgcn_s_setprio(1);
        #pragma unroll
        for (int ks = 0; ks < 2; ++ks) {
            s16x8 afh[2], afl[2];
            #pragma unroll
            for (int f = 0; f < 2; ++f) {
                int a = ix16(wave*32 + f*16 + lr, ks*32 + lg*8);
                afh[f] = *(const s16x8*)&Ah[a];
                afl[f] = *(const s16x8*)&Al[a];
            }
            #pragma unroll
            for (int t = 0; t < 8; ++t) {
                int bA = ix16(t*16 + lr, ks*32 + lg*8);
                s16x8 bfh = *(const s16x8*)&Bh[bA];
                s16x8 bfl = *(const s16x8*)&Bl[bA];
                #pragma unroll
                for (int f = 0; f < 2; ++f) {
                    acc[f][t] = MFMA16(afh[f], bfh, acc[f][t]);
                    acc[f][t] = MFMA16(afh[f], bfl, acc[f][t]);
                    acc[f][t] = MFMA16(afl[f], bfh, acc[f][t]);
                }
            }
        }
        __builtin_amdgcn_s_setprio(0);
    }

    float bb[8];
    #pragma unroll
    for (int t = 0; t < 8; ++t) bb[t] = bias[e0 + t*16 + lr];

    if (blockIdx.z == 0) {
        #pragma unroll
        for (int f = 0; f < 2; ++f)
            #pragma unroll
            for (int t = 0; t < 8; ++t)
                #pragma unroll
                for (int r = 0; r < 4; ++r) {
                    int row = m0 + wave*32 + f*16 + lg*4 + r;
                    Qout[(size_t)row * D_ + e0 + t*16 + lr] = acc[f][t][r] + bb[t];
                }
    } else {
        #pragma unroll
        for (int f = 0; f < 2; ++f)
            #pragma unroll
            for (int t = 0; t < 8; ++t)
                #pragma unroll
                for (int r = 0; r < 4; ++r) {
                    int row = m0 + wave*32 + f*16 + lg*4 + r;
                    float v = acc[f][t][r] + bb[t];
                    unsigned hh = bf16rtn(v);
                    float lo = v - bf16tof(hh);
                    unsigned ll = bf16rtn(lo);
                    size_t o = (size_t)row * D_ + e0 + t*16 + lr;
                    Khi[o] = (short)hh;
                    Klo[o] = (short)ll;
                }
    }
}

// ---------------------------------------------------------------------------
// FALLBACK projection (fp32 vector path) — used only if ws_size is too small
// for the split arrays. Same as round-4 kernel.
// ---------------------------------------------------------------------------
__global__ __launch_bounds__(256) void proj_kernel(
    const float* __restrict__ x,
    const float* __restrict__ Wq, const float* __restrict__ bq,
    const float* __restrict__ Wk, const float* __restrict__ bk,
    float* __restrict__ Qout, short* __restrict__ Khi, short* __restrict__ Klo)
{
    const float* W    = blockIdx.z ? Wk : Wq;
    const float* bias = blockIdx.z ? bk : bq;

    const int m0 = blockIdx.x * 128;
    const int e0 = blockIdx.y * 128;

    __shared__ float Xs[128][36];
    __shared__ float Ws[128 * 36];

    const int tid = threadIdx.x;
    const int tx = tid & 15, ty = tid >> 4;

    float acc[8][8] = {};

    for (int k0 = 0; k0 < D_; k0 += 32) {
        #pragma unroll
        for (int s = 0; s < 4; ++s) {
            int slot = s * 256 + tid;
            int r  = slot >> 3;
            int c4 = (slot & 7) << 2;
            *(float4*)&Xs[r][c4] = *(const float4*)&x[(size_t)(m0 + r) * D_ + k0 + c4];
            int wblk = ((c4 >> 2) ^ (r >> 3)) & 7;
            *(float4*)&Ws[r * 36 + wblk * 4] = *(const float4*)&W[(size_t)(e0 + r) * D_ + k0 + c4];
        }
        __syncthreads();
        #pragma unroll
        for (int k = 0; k < 32; k += 4) {
            float4 xa[8], wb[8];
            #pragma unroll
            for (int i = 0; i < 8; ++i) xa[i] = *(float4*)&Xs[ty*8+i][k];
            #pragma unroll
            for (int j = 0; j < 8; ++j) {
                int row = tx*8 + j;
                int blk = ((k >> 2) ^ (row >> 3)) & 7;
                wb[j] = *(float4*)&Ws[row * 36 + blk * 4];
            }
            #pragma unroll
            for (int i = 0; i < 8; ++i)
                #pragma unroll
                for (int j = 0; j < 8; ++j)
                    acc[i][j] += xa[i].x*wb[j].x + xa[i].y*wb[j].y
                               + xa[i].z*wb[j].z + xa[i].w*wb[j].w;
        }
        __syncthreads();
    }

    const float4 bv0 = *(const float4*)&bias[e0 + tx*8];
    const float4 bv1 = *(const float4*)&bias[e0 + tx*8 + 4];
    const float bj[8] = {bv0.x,bv0.y,bv0.z,bv0.w, bv1.x,bv1.y,bv1.z,bv1.w};

    if (blockIdx.z == 0) {
        #pragma unroll
        for (int i = 0; i < 8; ++i) {
            float o[8];
            #pragma unroll
            for (int j = 0; j < 8; ++j) o[j] = acc[i][j] + bj[j];
            size_t off = (size_t)(m0 + ty*8 + i) * D_ + e0 + tx*8;
            *(float4*)&Qout[off]     = *(float4*)&o[0];
            *(float4*)&Qout[off + 4] = *(float4*)&o[4];
        }
    } else {
        #pragma unroll
        for (int i = 0; i < 8; ++i) {
            s16x8 oh, ol;
            #pragma unroll
            for (int j = 0; j < 8; ++j) {
                float v = acc[i][j] + bj[j];
                unsigned hh = bf16rtn(v);
                float lo = v - bf16tof(hh);
                unsigned ll = bf16rtn(lo);
                oh[j] = (short)hh; ol[j] = (short)ll;
            }
            size_t off = (size_t)(m0 + ty*8 + i) * D_ + e0 + tx*8;
            *(s16x8*)&Khi[off] = oh;
            *(s16x8*)&Klo[off] = ol;
        }
    }
}

// ---------------------------------------------------------------------------
// Flash attention, bf16x3 split MFMA, V = K. QBLK=128 (4 waves x 2 q-frags),
// KVBLK=64, software-prefetched K staging, 2 barriers/iter. (unchanged)
// ---------------------------------------------------------------------------
__global__ __launch_bounds__(256, 2) void attn_kernel(
    const float* __restrict__ Q,
    const short* __restrict__ Khi, const short* __restrict__ Klo,
    float* __restrict__ out)
{
    __shared__ short Khs[4096];      // [key][d] hi   (ix16)
    __shared__ short Kls[4096];      // [key][d] lo
    __shared__ short Kths[4096];     // [d][key] hi   (ixt)
    __shared__ short Ktls[4096];     // [d][key] lo
    __shared__ unsigned Pp[8192];    // [128 q][64 k] packed (ixp)

    const int bid = blockIdx.x;
    const int xcd = bid & 7, kk = bid >> 3;
    const int bh  = (xcd << 1) | (kk >> 5);
    const int qt  = kk & 31;
    const int b = bh >> 3, h = bh & 7;
    const int q0 = qt * 128;

    const int tid  = threadIdx.x;
    const int wave = tid >> 6, lane = tid & 63;
    const int lr = lane & 15, lg = lane >> 4;

    s16x8 qh[2][2], ql[2][2];
    #pragma unroll
    for (int f = 0; f < 2; ++f) {
        const int qrow = q0 + wave*32 + f*16 + lr;
        const float* qp = Q + ((size_t)(b*N_ + qrow)) * D_ + h*HD_;
        #pragma unroll
        for (int ks = 0; ks < 2; ++ks) {
            const float* p = qp + ks*32 + lg*8;
            float4 a = *(const float4*)p;
            float4 c = *(const float4*)(p + 4);
            float v[8] = {a.x,a.y,a.z,a.w,c.x,c.y,c.z,c.w};
            #pragma unroll
            for (int j = 0; j < 8; ++j) {
                float xv = v[j] * SCL2;
                unsigned hh = bf16rtn(xv);
                float lo = xv - bf16tof(hh);
                unsigned ll = bf16rtn(lo);
                qh[f][ks][j] = (short)hh; ql[f][ks][j] = (short)ll;
            }
        }
    }

    f32x4 oacc[2][4] = {};
    float mrun[2][4], lrun[2][4];
    #pragma unroll
    for (int f = 0; f < 2; ++f)
        #pragma unroll
        for (int r = 0; r < 4; ++r) { mrun[f][r] = -1e30f; lrun[f][r] = 0.f; }

    const int br = tid >> 4, bc = tid & 15;
    s16x4 rh[4], rl[4];

    {   // prefetch tile 0
        const size_t kbase = ((size_t)(b*N_ + br*4)) * D_ + h*HD_ + bc*4;
        #pragma unroll
        for (int i = 0; i < 4; ++i) {
            rh[i] = *(const s16x4*)&Khi[kbase + (size_t)i * D_];
            rl[i] = *(const s16x4*)&Klo[kbase + (size_t)i * D_];
        }
    }

    for (int kt = 0; kt < 64; ++kt) {
        #pragma unroll
        for (int i = 0; i < 4; ++i) {
            *(s16x4*)&Khs[ix16(br*4+i, bc*4)] = rh[i];
            *(s16x4*)&Kls[ix16(br*4+i, bc*4)] = rl[i];
        }
        #pragma unroll
        for (int j = 0; j < 4; ++j) {
            s16x4 th = { rh[0][j], rh[1][j], rh[2][j], rh[3][j] };
            s16x4 tl = { rl[0][j], rl[1][j], rl[2][j], rl[3][j] };
            *(s16x4*)&Kths[ixt(bc*4+j, br*4)] = th;
            *(s16x4*)&Ktls[ixt(bc*4+j, br*4)] = tl;
        }
        __syncthreads();

        if (kt < 63) {
            const size_t kbase = ((size_t)(b*N_ + (kt+1)*64 + br*4)) * D_ + h*HD_ + bc*4;
            #pragma unroll
            for (int i = 0; i < 4; ++i) {
                rh[i] = *(const s16x4*)&Khi[kbase + (size_t)i * D_];
                rl[i] = *(const s16x4*)&Klo[kbase + (size_t)i * D_];
            }
        }

        f32x4 sacc[2][4] = {};
        __builtin_amdgcn_s_setprio(1);
        #pragma unroll
        for (int ks = 0; ks < 2; ++ks) {
            s16x8 kbh[4], kbl[4];
            #pragma unroll
            for (int t = 0; t < 4; ++t) {
                kbh[t] = *(const s16x8*)&Khs[ix16(t*16+lr, ks*32+lg*8)];
                kbl[t] = *(const s16x8*)&Kls[ix16(t*16+lr, ks*32+lg*8)];
            }
            #pragma unroll
            for (int f = 0; f < 2; ++f) {
                #pragma unroll
                for (int t = 0; t < 4; ++t) sacc[f][t] = MFMA16(qh[f][ks], kbh[t], sacc[f][t]);
                #pragma unroll
                for (int t = 0; t < 4; ++t) sacc[f][t] = MFMA16(qh[f][ks], kbl[t], sacc[f][t]);
                #pragma unroll
                for (int t = 0; t < 4; ++t) sacc[f][t] = MFMA16(ql[f][ks], kbh[t], sacc[f][t]);
            }
        }
        __builtin_amdgcn_s_setprio(0);

        #pragma unroll
        for (int f = 0; f < 2; ++f) {
            float mt[4];
            #pragma unroll
            for (int r = 0; r < 4; ++r)
                mt[r] = fmaxf(fmaxf(sacc[f][0][r], sacc[f][1][r]),
                              fmaxf(sacc[f][2][r], sacc[f][3][r]));
            #pragma unroll
            for (int r = 0; r < 4; ++r)
                #pragma unroll
                for (int msk = 1; msk < 16; msk <<= 1)
                    mt[r] = fmaxf(mt[r], __shfl_xor(mt[r], msk));
            float al[4];
            #pragma unroll
            for (int r = 0; r < 4; ++r) {
                float mn = fmaxf(mrun[f][r], mt[r]);
                al[r] = __builtin_amdgcn_exp2f(mrun[f][r] - mn);
                mrun[f][r] = mn;
            }
            float rs[4] = {0.f, 0.f, 0.f, 0.f};
            #pragma unroll
            for (int t = 0; t < 4; ++t)
                #pragma unroll
                for (int r = 0; r < 4; ++r) {
                    float p = __builtin_amdgcn_exp2f(sacc[f][t][r] - mrun[f][r]);
                    rs[r] += p;
                    unsigned u  = __float_as_uint(p);
                    unsigned uh = u & 0xFFFF0000u;
                    unsigned ul = __float_as_uint(p - __uint_as_float(uh));
                    Pp[ixp(wave*32 + f*16 + lg*4 + r, t*16 + lr)] = uh | (ul >> 16);
                }
            #pragma unroll
            for (int r = 0; r < 4; ++r) {
                #pragma unroll
                for (int msk = 1; msk < 16; msk <<= 1)
                    rs[r] += __shfl_xor(rs[r], msk);
                lrun[f][r] = lrun[f][r] * al[r] + rs[r];
            }
            #pragma unroll
            for (int t = 0; t < 4; ++t)
                #pragma unroll
                for (int r = 0; r < 4; ++r)
                    oacc[f][t][r] *= al[r];
        }

        __builtin_amdgcn_s_setprio(1);
        #pragma unroll
        for (int ks = 0; ks < 2; ++ks) {
            s16x8 vbh[4], vbl[4];
            #pragma unroll
            for (int t = 0; t < 4; ++t) {
                vbh[t] = *(const s16x8*)&Kths[ixt(t*16+lr, ks*32+lg*8)];
                vbl[t] = *(const s16x8*)&Ktls[ixt(t*16+lr, ks*32+lg*8)];
            }
            #pragma unroll
            for (int f = 0; f < 2; ++f) {
                const int prow = wave*32 + f*16 + lr;
                u32x4 a = *(const u32x4*)&Pp[ixp(prow, ks*32 + lg*8)];
                u32x4 c = *(const u32x4*)&Pp[ixp(prow, ks*32 + lg*8 + 4)];
                s16x8 pah, pal;
                #pragma unroll
                for (int i = 0; i < 4; ++i) {
                    pah[i]   = (short)(a[i] >> 16);
                    pal[i]   = (short)(a[i] & 0xFFFFu);
                    pah[4+i] = (short)(c[i] >> 16);
                    pal[4+i] = (short)(c[i] & 0xFFFFu);
                }
                #pragma unroll
                for (int t = 0; t < 4; ++t) oacc[f][t] = MFMA16(pah, vbh[t], oacc[f][t]);
                #pragma unroll
                for (int t = 0; t < 4; ++t) oacc[f][t] = MFMA16(pah, vbl[t], oacc[f][t]);
                #pragma unroll
                for (int t = 0; t < 4; ++t) oacc[f][t] = MFMA16(pal, vbh[t], oacc[f][t]);
            }
        }
        __builtin_amdgcn_s_setprio(0);
        __syncthreads();
    }

    #pragma unroll
    for (int f = 0; f < 2; ++f)
        #pragma unroll
        for (int r = 0; r < 4; ++r) {
            const float inv = 1.0f / lrun[f][r];
            const int row = q0 + wave*32 + f*16 + lg*4 + r;
            float* op = out + ((size_t)(b*N_ + row)) * D_ + h*HD_;
            #pragma unroll
            for (int t = 0; t < 4; ++t)
                op[t*16 + lr] = oacc[f][t][r] * inv;
        }
}

extern "C" void kernel_launch(void* const* d_in, const int* in_sizes, int n_in,
                              void* d_out, int out_size, void* d_ws, size_t ws_size,
                              hipStream_t stream)
{
    const float* x  = (const float*)d_in[0];
    const float* Wq = (const float*)d_in[1];
    const float* bq = (const float*)d_in[2];
    const float* Wk = (const float*)d_in[3];
    const float* bk = (const float*)d_in[4];
    float* outp = (float*)d_out;

    // ws layout:
    //   [0,        16777216)  Qw   fp32
    //   [16777216, 33554432)  Khi|Klo bf16
    //   [33554432, 50331648)  xh|xl   bf16   (MFMA path only)
    //   [50331648, 52428800)  wqh|wql|wkh|wkl bf16
    char* wsb = (char*)d_ws;
    float* Qw  = (float*)wsb;
    short* Khi = (short*)(wsb + 16777216);
    short* Klo = Khi + 4194304;

    if (ws_size >= 52428800) {
        short* xh  = (short*)(wsb + 33554432);
        short* xl  = xh + 4194304;
        short* wqh = (short*)(wsb + 50331648);
        short* wql = wqh + 262144;
        short* wkh = wql + 262144;
        short* wkl = wkh + 262144;

        split_kernel<<<dim3(2304), dim3(256), 0, stream>>>(
            x, Wq, Wk, xh, xl, wqh, wql, wkh, wkl);
        proj_gemm<<<dim3(64, 4, 2), dim3(256), 0, stream>>>(
            xh, xl, wqh, wql, wkh, wkl, bq, bk, Qw, Khi, Klo);
    } else {
        dim3 gp(64, 4, 2);
        proj_kernel<<<gp, dim3(256), 0, stream>>>(x, Wq, bq, Wk, bk, Qw, Khi, Klo);
    }

    attn_kernel<<<dim3(512), dim3(256), 0, stream>>>(Qw, Khi, Klo, outp);
}

// Round 6
// 317.679 us; speedup vs baseline: 6.4000x; 1.1693x over previous
//
#include <hip/hip_runtime.h>

#define B_  2
#define N_  4096
#define D_  512
#define H_  8
#define HD_ 64
// (D^-0.5) * log2(e): fold softmax scale AND exp->exp2 conversion into Q
#define SCL2 (0.04419417382415922f * 1.4426950408889634f)

typedef float  f32x4  __attribute__((ext_vector_type(4)));
typedef float  f32x16 __attribute__((ext_vector_type(16)));
typedef short  s16x8  __attribute__((ext_vector_type(8)));
typedef short  s16x4  __attribute__((ext_vector_type(4)));
typedef unsigned int u32x4 __attribute__((ext_vector_type(4)));

#define MFMA16(a,b,c) __builtin_amdgcn_mfma_f32_16x16x32_bf16((a),(b),(c),0,0,0)
#define MFMA32(a,b,c) __builtin_amdgcn_mfma_f32_32x32x16_bf16((a),(b),(c),0,0,0)

__device__ __forceinline__ unsigned bf16rtn(float x){
    unsigned u = __float_as_uint(x);
    return (u + 0x7FFFu + ((u >> 16) & 1u)) >> 16;
}
__device__ __forceinline__ float bf16tof(unsigned h){
    return __uint_as_float(h << 16);
}
// pack two f32 -> (bf16(lo) | bf16(hi)<<16), RTN. No builtin on gfx950.
__device__ __forceinline__ unsigned cvt_pk_bf16(float lo, float hi){
    unsigned r;
    asm("v_cvt_pk_bf16_f32 %0, %1, %2" : "=v"(r) : "v"(lo), "v"(hi));
    return r;
}
// swap a[lanes 32..63] <-> b[lanes 0..31]  (LLVM: permlane32.swap semantics)
__device__ __forceinline__ void perm32swap(unsigned &a, unsigned &b){
    asm volatile("v_permlane32_swap_b32 %0, %1" : "+v"(a), "+v"(b));
}
// [*][64] bf16 arrays: XOR-swizzle 8-elem (16B) blocks with row&7
__device__ __forceinline__ int ix16(int r, int c){
    return (r << 6) + ((((c >> 3) ^ (r & 7)) << 3) | (c & 7));
}
// transposed arrays: extra ^(r>>3) so transpose-WRITES spread over 32 banks
__device__ __forceinline__ int ixt(int r, int c){
    return (r << 6) + ((((c >> 3) ^ (r & 7) ^ ((r >> 3) & 7)) << 3) | (c & 7));
}

// ---------------------------------------------------------------------------
// Split pass: fp32 -> (bf16 hi, bf16 lo) for x, Wq, Wk. Pure streaming.
// ---------------------------------------------------------------------------
__global__ __launch_bounds__(256) void split_kernel(
    const float* __restrict__ x, const float* __restrict__ Wq, const float* __restrict__ Wk,
    short* __restrict__ xh, short* __restrict__ xl,
    short* __restrict__ wqh, short* __restrict__ wql,
    short* __restrict__ wkh, short* __restrict__ wkl)
{
    const int bid = blockIdx.x;
    const float* src; short* dh; short* dl; size_t base;
    if (bid < 2048)      { src = x;  dh = xh;  dl = xl;  base = (size_t)bid * 2048; }
    else if (bid < 2176) { src = Wq; dh = wqh; dl = wql; base = (size_t)(bid - 2048) * 2048; }
    else                 { src = Wk; dh = wkh; dl = wkl; base = (size_t)(bid - 2176) * 2048; }

    const size_t off = base + (size_t)threadIdx.x * 8;
    float4 a = *(const float4*)&src[off];
    float4 c = *(const float4*)&src[off + 4];
    float v[8] = {a.x,a.y,a.z,a.w, c.x,c.y,c.z,c.w};
    s16x8 oh, ol;
    #pragma unroll
    for (int j = 0; j < 8; ++j) {
        unsigned hh = bf16rtn(v[j]);
        float lo = v[j] - bf16tof(hh);
        unsigned ll = bf16rtn(lo);
        oh[j] = (short)hh; ol[j] = (short)ll;
    }
    *(s16x8*)&dh[off] = oh;
    *(s16x8*)&dl[off] = ol;
}

// ---------------------------------------------------------------------------
// Projection GEMM on MFMA, bf16x3 split precision. (unchanged from r5)
// ---------------------------------------------------------------------------
__global__ __launch_bounds__(256, 2) void proj_gemm(
    const short* __restrict__ xh, const short* __restrict__ xl,
    const short* __restrict__ wqh, const short* __restrict__ wql,
    const short* __restrict__ wkh, const short* __restrict__ wkl,
    const float* __restrict__ bq, const float* __restrict__ bk,
    float* __restrict__ Qout, short* __restrict__ Khi, short* __restrict__ Klo)
{
    __shared__ short Ah[8192], Al[8192], Bh[8192], Bl[8192];   // [128][64] ix16

    const short* gWh  = blockIdx.z ? wkh : wqh;
    const short* gWl  = blockIdx.z ? wkl : wql;
    const float* bias = blockIdx.z ? bk  : bq;

    const int m0 = blockIdx.x * 128;
    const int e0 = blockIdx.y * 128;
    const int tid = threadIdx.x;
    const int wave = tid >> 6, lane = tid & 63;
    const int lr = lane & 15, lg = lane >> 4;

    int srow[4], scol[4];
    #pragma unroll
    for (int s = 0; s < 4; ++s) {
        int slot = s * 256 + tid;
        srow[s] = slot >> 3;
        scol[s] = (slot & 7) << 3;
    }

    f32x4 acc[2][8] = {};
    s16x8 pah[4], pal[4], pbh[4], pbl[4];

    #pragma unroll
    for (int s = 0; s < 4; ++s) {
        size_t ao = (size_t)(m0 + srow[s]) * D_ + scol[s];
        size_t bo = (size_t)(e0 + srow[s]) * D_ + scol[s];
        pah[s] = *(const s16x8*)&xh[ao];  pal[s] = *(const s16x8*)&xl[ao];
        pbh[s] = *(const s16x8*)&gWh[bo]; pbl[s] = *(const s16x8*)&gWl[bo];
    }

    for (int kt = 0; kt < 8; ++kt) {
        if (kt) __syncthreads();
        #pragma unroll
        for (int s = 0; s < 4; ++s) {
            int d = ix16(srow[s], scol[s]);
            *(s16x8*)&Ah[d] = pah[s];  *(s16x8*)&Al[d] = pal[s];
            *(s16x8*)&Bh[d] = pbh[s];  *(s16x8*)&Bl[d] = pbl[s];
        }
        __syncthreads();
        if (kt < 7) {
            const int k0 = (kt + 1) * 64;
            #pragma unroll
            for (int s = 0; s < 4; ++s) {
                size_t ao = (size_t)(m0 + srow[s]) * D_ + k0 + scol[s];
                size_t bo = (size_t)(e0 + srow[s]) * D_ + k0 + scol[s];
                pah[s] = *(const s16x8*)&xh[ao];  pal[s] = *(const s16x8*)&xl[ao];
                pbh[s] = *(const s16x8*)&gWh[bo]; pbl[s] = *(const s16x8*)&gWl[bo];
            }
        }
        __builtin_amdgcn_s_setprio(1);
        #pragma unroll
        for (int ks = 0; ks < 2; ++ks) {
            s16x8 afh[2], afl[2];
            #pragma unroll
            for (int f = 0; f < 2; ++f) {
                int a = ix16(wave*32 + f*16 + lr, ks*32 + lg*8);
                afh[f] = *(const s16x8*)&Ah[a];
                afl[f] = *(const s16x8*)&Al[a];
            }
            #pragma unroll
            for (int t = 0; t < 8; ++t) {
                int bA = ix16(t*16 + lr, ks*32 + lg*8);
                s16x8 bfh = *(const s16x8*)&Bh[bA];
                s16x8 bfl = *(const s16x8*)&Bl[bA];
                #pragma unroll
                for (int f = 0; f < 2; ++f) {
                    acc[f][t] = MFMA16(afh[f], bfh, acc[f][t]);
                    acc[f][t] = MFMA16(afh[f], bfl, acc[f][t]);
                    acc[f][t] = MFMA16(afl[f], bfh, acc[f][t]);
                }
            }
        }
        __builtin_amdgcn_s_setprio(0);
    }

    float bb[8];
    #pragma unroll
    for (int t = 0; t < 8; ++t) bb[t] = bias[e0 + t*16 + lr];

    if (blockIdx.z == 0) {
        #pragma unroll
        for (int f = 0; f < 2; ++f)
            #pragma unroll
            for (int t = 0; t < 8; ++t)
                #pragma unroll
                for (int r = 0; r < 4; ++r) {
                    int row = m0 + wave*32 + f*16 + lg*4 + r;
                    Qout[(size_t)row * D_ + e0 + t*16 + lr] = acc[f][t][r] + bb[t];
                }
    } else {
        #pragma unroll
        for (int f = 0; f < 2; ++f)
            #pragma unroll
            for (int t = 0; t < 8; ++t)
                #pragma unroll
                for (int r = 0; r < 4; ++r) {
                    int row = m0 + wave*32 + f*16 + lg*4 + r;
                    float v = acc[f][t][r] + bb[t];
                    unsigned hh = bf16rtn(v);
                    float lo = v - bf16tof(hh);
                    unsigned ll = bf16rtn(lo);
                    size_t o = (size_t)row * D_ + e0 + t*16 + lr;
                    Khi[o] = (short)hh;
                    Klo[o] = (short)ll;
                }
    }
}

// ---------------------------------------------------------------------------
// FALLBACK projection (fp32 vector path) — only if ws_size is too small.
// ---------------------------------------------------------------------------
__global__ __launch_bounds__(256) void proj_kernel(
    const float* __restrict__ x,
    const float* __restrict__ Wq, const float* __restrict__ bq,
    const float* __restrict__ Wk, const float* __restrict__ bk,
    float* __restrict__ Qout, short* __restrict__ Khi, short* __restrict__ Klo)
{
    const float* W    = blockIdx.z ? Wk : Wq;
    const float* bias = blockIdx.z ? bk : bq;

    const int m0 = blockIdx.x * 128;
    const int e0 = blockIdx.y * 128;

    __shared__ float Xs[128][36];
    __shared__ float Ws[128 * 36];

    const int tid = threadIdx.x;
    const int tx = tid & 15, ty = tid >> 4;

    float acc[8][8] = {};

    for (int k0 = 0; k0 < D_; k0 += 32) {
        #pragma unroll
        for (int s = 0; s < 4; ++s) {
            int slot = s * 256 + tid;
            int r  = slot >> 3;
            int c4 = (slot & 7) << 2;
            *(float4*)&Xs[r][c4] = *(const float4*)&x[(size_t)(m0 + r) * D_ + k0 + c4];
            int wblk = ((c4 >> 2) ^ (r >> 3)) & 7;
            *(float4*)&Ws[r * 36 + wblk * 4] = *(const float4*)&W[(size_t)(e0 + r) * D_ + k0 + c4];
        }
        __syncthreads();
        #pragma unroll
        for (int k = 0; k < 32; k += 4) {
            float4 xa[8], wb[8];
            #pragma unroll
            for (int i = 0; i < 8; ++i) xa[i] = *(float4*)&Xs[ty*8+i][k];
            #pragma unroll
            for (int j = 0; j < 8; ++j) {
                int row = tx*8 + j;
                int blk = ((k >> 2) ^ (row >> 3)) & 7;
                wb[j] = *(float4*)&Ws[row * 36 + blk * 4];
            }
            #pragma unroll
            for (int i = 0; i < 8; ++i)
                #pragma unroll
                for (int j = 0; j < 8; ++j)
                    acc[i][j] += xa[i].x*wb[j].x + xa[i].y*wb[j].y
                               + xa[i].z*wb[j].z + xa[i].w*wb[j].w;
        }
        __syncthreads();
    }

    const float4 bv0 = *(const float4*)&bias[e0 + tx*8];
    const float4 bv1 = *(const float4*)&bias[e0 + tx*8 + 4];
    const float bj[8] = {bv0.x,bv0.y,bv0.z,bv0.w, bv1.x,bv1.y,bv1.z,bv1.w};

    if (blockIdx.z == 0) {
        #pragma unroll
        for (int i = 0; i < 8; ++i) {
            float o[8];
            #pragma unroll
            for (int j = 0; j < 8; ++j) o[j] = acc[i][j] + bj[j];
            size_t off = (size_t)(m0 + ty*8 + i) * D_ + e0 + tx*8;
            *(float4*)&Qout[off]     = *(float4*)&o[0];
            *(float4*)&Qout[off + 4] = *(float4*)&o[4];
        }
    } else {
        #pragma unroll
        for (int i = 0; i < 8; ++i) {
            s16x8 oh, ol;
            #pragma unroll
            for (int j = 0; j < 8; ++j) {
                float v = acc[i][j] + bj[j];
                unsigned hh = bf16rtn(v);
                float lo = v - bf16tof(hh);
                unsigned ll = bf16rtn(lo);
                oh[j] = (short)hh; ol[j] = (short)ll;
            }
            size_t off = (size_t)(m0 + ty*8 + i) * D_ + e0 + tx*8;
            *(s16x8*)&Khi[off] = oh;
            *(s16x8*)&Klo[off] = ol;
        }
    }
}

// ---------------------------------------------------------------------------
// Flash attention, 32x32x16 MFMA, swapped operands, V = K.
// QBLK=128 (4 waves x 32 q), KVBLK=64. QK^T: D[k][q] (q=lane&31). Softmax
// fully lane-local (1 shfl per reduce). P packed in-register via
// cvt_pk_bf16 + permlane32_swap -> PV B-frags (no LDS round-trip).
// PV swapped: O^T[d][q], epilogue transposes through reused K-LDS.
// ---------------------------------------------------------------------------
__global__ __launch_bounds__(256, 2) void attn_kernel(
    const float* __restrict__ Q,
    const short* __restrict__ Khi, const short* __restrict__ Klo,
    float* __restrict__ out)
{
    __shared__ __align__(16) char smem[32768];
    short* Khs  = (short*)smem;          // [64][64] hi  (ix16)
    short* Kls  = Khs + 4096;            // lo
    short* Kths = Kls + 4096;            // [d][k] hi    (ixt)
    short* Ktls = Kths + 4096;           // lo

    // XCD-chunked swizzle: 2 (b,h) per XCD
    const int bid = blockIdx.x;
    const int xcd = bid & 7, kk = bid >> 3;
    const int bh  = (xcd << 1) | (kk >> 5);
    const int qt  = kk & 31;
    const int b = bh >> 3, h = bh & 7;
    const int q0 = qt * 128;

    const int tid  = threadIdx.x;
    const int wave = tid >> 6, lane = tid & 63;
    const int lq   = lane & 31;          // q index (and k/d row within tile)
    const int hi   = lane >> 5;          // k-chunk half selector

    // ---- Q B-frags: b[j] = Q'[d = 16s + 8hi + j][q=lq], pre-scaled, split ----
    s16x8 qbh[4], qbl[4];
    {
        const int qrow = q0 + wave*32 + lq;
        const float* qp = Q + ((size_t)(b*N_ + qrow)) * D_ + h*HD_ + hi*8;
        #pragma unroll
        for (int s = 0; s < 4; ++s) {
            float4 a = *(const float4*)(qp + s*16);
            float4 c = *(const float4*)(qp + s*16 + 4);
            float v[8] = {a.x,a.y,a.z,a.w,c.x,c.y,c.z,c.w};
            #pragma unroll
            for (int j = 0; j < 8; ++j) {
                float xv = v[j] * SCL2;
                unsigned hh = bf16rtn(xv);
                float lo = xv - bf16tof(hh);
                qbh[s][j] = (short)hh;
                qbl[s][j] = (short)bf16rtn(lo);
            }
        }
    }

    f32x16 oacc[2] = {};                 // O^T[d][q=lq], d-rows per reg map
    float mrun = -1e30f, lrun = 0.f;

    const int br = tid >> 4, bc = tid & 15;   // staging: 4x4 block per thread
    s16x4 rh[4], rl[4];

    {   // prefetch tile 0
        const size_t kbase = ((size_t)(b*N_ + br*4)) * D_ + h*HD_ + bc*4;
        #pragma unroll
        for (int i = 0; i < 4; ++i) {
            rh[i] = *(const s16x4*)&Khi[kbase + (size_t)i * D_];
            rl[i] = *(const s16x4*)&Klo[kbase + (size_t)i * D_];
        }
    }

    for (int kt = 0; kt < 64; ++kt) {
        // ---- stage prefetched K tile (direct + transposed) ----
        #pragma unroll
        for (int i = 0; i < 4; ++i) {
            *(s16x4*)&Khs[ix16(br*4+i, bc*4)] = rh[i];
            *(s16x4*)&Kls[ix16(br*4+i, bc*4)] = rl[i];
        }
        #pragma unroll
        for (int j = 0; j < 4; ++j) {
            s16x4 th = { rh[0][j], rh[1][j], rh[2][j], rh[3][j] };
            s16x4 tl = { rl[0][j], rl[1][j], rl[2][j], rl[3][j] };
            *(s16x4*)&Kths[ixt(bc*4+j, br*4)] = th;
            *(s16x4*)&Ktls[ixt(bc*4+j, br*4)] = tl;
        }
        __syncthreads();

        // ---- prefetch next tile ----
        if (kt < 63) {
            const size_t kbase = ((size_t)(b*N_ + (kt+1)*64 + br*4)) * D_ + h*HD_ + bc*4;
            #pragma unroll
            for (int i = 0; i < 4; ++i) {
                rh[i] = *(const s16x4*)&Khi[kbase + (size_t)i * D_];
                rl[i] = *(const s16x4*)&Klo[kbase + (size_t)i * D_];
            }
        }

        // ---- S^T = K Q' : D[k][q], bf16x3 ----
        f32x16 sacc[2] = {};
        __builtin_amdgcn_s_setprio(1);
        #pragma unroll
        for (int t = 0; t < 2; ++t) {
            #pragma unroll
            for (int s = 0; s < 4; ++s) {
                s16x8 ah = *(const s16x8*)&Khs[ix16(t*32 + lq, s*16 + hi*8)];
                s16x8 al = *(const s16x8*)&Kls[ix16(t*32 + lq, s*16 + hi*8)];
                sacc[t] = MFMA32(ah, qbh[s], sacc[t]);
                sacc[t] = MFMA32(ah, qbl[s], sacc[t]);
                sacc[t] = MFMA32(al, qbh[s], sacc[t]);
            }
        }
        __builtin_amdgcn_s_setprio(0);

        // ---- online softmax, lane-local (base-2 units) ----
        float tr[16];
        #pragma unroll
        for (int r = 0; r < 16; ++r) tr[r] = fmaxf(sacc[0][r], sacc[1][r]);
        #pragma unroll
        for (int st = 8; st >= 1; st >>= 1)
            #pragma unroll
            for (int r = 0; r < st; ++r) tr[r] = fmaxf(tr[r], tr[r + st]);
        float mt = fmaxf(tr[0], __shfl_xor(tr[0], 32));
        const float mn  = fmaxf(mrun, mt);
        const float al_ = __builtin_amdgcn_exp2f(mrun - mn);
        mrun = mn;

        f32x16 p[2];
        #pragma unroll
        for (int t = 0; t < 2; ++t)
            #pragma unroll
            for (int r = 0; r < 16; ++r)
                p[t][r] = __builtin_amdgcn_exp2f(sacc[t][r] - mn);
        #pragma unroll
        for (int r = 0; r < 16; ++r) tr[r] = p[0][r] + p[1][r];
        #pragma unroll
        for (int st = 8; st >= 1; st >>= 1)
            #pragma unroll
            for (int r = 0; r < st; ++r) tr[r] += tr[r + st];
        float rs = tr[0] + __shfl_xor(tr[0], 32);
        lrun = lrun * al_ + rs;
        #pragma unroll
        for (int dt = 0; dt < 2; ++dt)
            #pragma unroll
            for (int r = 0; r < 16; ++r)
                oacc[dt][r] *= al_;

        // ---- O^T += V^T P^T : per 16-k step, P assembled in-register ----
        __builtin_amdgcn_s_setprio(1);
        #pragma unroll
        for (int s = 0; s < 4; ++s) {
            const int tt = s >> 1, r0 = (s & 1) * 8;
            float ph[8], pl[8];
            #pragma unroll
            for (int j = 0; j < 8; ++j) {
                float pv = p[tt][r0 + j];
                float hf = __uint_as_float(__float_as_uint(pv) & 0xFFFF0000u);
                ph[j] = hf;
                pl[j] = pv - hf;
            }
            unsigned h0 = cvt_pk_bf16(ph[0], ph[1]);
            unsigned h1 = cvt_pk_bf16(ph[4], ph[5]);
            perm32swap(h0, h1);              // h0=(k01|k89) h1=(k45|k12,13)
            unsigned h2 = cvt_pk_bf16(ph[2], ph[3]);
            unsigned h3 = cvt_pk_bf16(ph[6], ph[7]);
            perm32swap(h2, h3);
            u32x4 wph = { h0, h2, h1, h3 };
            s16x8 pfh = __builtin_bit_cast(s16x8, wph);

            unsigned l0 = cvt_pk_bf16(pl[0], pl[1]);
            unsigned l1 = cvt_pk_bf16(pl[4], pl[5]);
            perm32swap(l0, l1);
            unsigned l2 = cvt_pk_bf16(pl[2], pl[3]);
            unsigned l3 = cvt_pk_bf16(pl[6], pl[7]);
            perm32swap(l2, l3);
            u32x4 wpl = { l0, l2, l1, l3 };
            s16x8 pfl = __builtin_bit_cast(s16x8, wpl);

            #pragma unroll
            for (int dt = 0; dt < 2; ++dt) {
                s16x8 vh = *(const s16x8*)&Kths[ixt(dt*32 + lq, s*16 + hi*8)];
                s16x8 vl = *(const s16x8*)&Ktls[ixt(dt*32 + lq, s*16 + hi*8)];
                oacc[dt] = MFMA32(vh, pfh, oacc[dt]);
                oacc[dt] = MFMA32(vl, pfh, oacc[dt]);
                oacc[dt] = MFMA32(vh, pfl, oacc[dt]);
            }
        }
        __builtin_amdgcn_s_setprio(0);
        __syncthreads();
    }

    // ---- epilogue: O /= l; transpose via reused LDS; coalesced store ----
    const float inv = 1.0f / lrun;
    float* Os = (float*)smem;               // [128][64], 4-block XOR swizzle
    #pragma unroll
    for (int dt = 0; dt < 2; ++dt)
        #pragma unroll
        for (int g = 0; g < 4; ++g) {
            f32x4 w;
            #pragma unroll
            for (int e = 0; e < 4; ++e)
                w[e] = oacc[dt][g*4 + e] * inv;
            const int q = wave*32 + lq;
            const int dbase = dt*32 + g*8 + hi*4;
            *(f32x4*)&Os[q*64 + (dbase ^ (q & 28))] = w;
        }
    __syncthreads();
    #pragma unroll
    for (int rep = 0; rep < 8; ++rep) {
        const int row = (tid >> 4) + rep*16;
        const int c4  = (tid & 15) * 4;
        f32x4 w = *(const f32x4*)&Os[row*64 + (c4 ^ (row & 28))];
        *(f32x4*)&out[((size_t)(b*N_ + q0 + row)) * D_ + h*HD_ + c4] = w;
    }
}

extern "C" void kernel_launch(void* const* d_in, const int* in_sizes, int n_in,
                              void* d_out, int out_size, void* d_ws, size_t ws_size,
                              hipStream_t stream)
{
    const float* x  = (const float*)d_in[0];
    const float* Wq = (const float*)d_in[1];
    const float* bq = (const float*)d_in[2];
    const float* Wk = (const float*)d_in[3];
    const float* bk = (const float*)d_in[4];
    float* outp = (float*)d_out;

    char* wsb = (char*)d_ws;
    float* Qw  = (float*)wsb;
    short* Khi = (short*)(wsb + 16777216);
    short* Klo = Khi + 4194304;

    if (ws_size >= 52428800) {
        short* xh  = (short*)(wsb + 33554432);
        short* xl  = xh + 4194304;
        short* wqh = (short*)(wsb + 50331648);
        short* wql = wqh + 262144;
        short* wkh = wql + 262144;
        short* wkl = wkh + 262144;

        split_kernel<<<dim3(2304), dim3(256), 0, stream>>>(
            x, Wq, Wk, xh, xl, wqh, wql, wkh, wkl);
        proj_gemm<<<dim3(64, 4, 2), dim3(256), 0, stream>>>(
            xh, xl, wqh, wql, wkh, wkl, bq, bk, Qw, Khi, Klo);
    } else {
        dim3 gp(64, 4, 2);
        proj_kernel<<<gp, dim3(256), 0, stream>>>(x, Wq, bq, Wk, bk, Qw, Khi, Klo);
    }

    attn_kernel<<<dim3(512), dim3(256), 0, stream>>>(Qw, Khi, Klo, outp);
}